// Round 11
// baseline (50.276 us; speedup 1.0000x reference)
//
#include <hip/hip_runtime.h>
#include <hip/hip_bf16.h>

// Problem constants: N=8, C=4096, H=768, O=768, K=1024
#define N_B 8
#define C_C 4096
#define H_H 768
#define O_O 768
#define K_K 1024
#define M_TOT (N_B * K_K)        // 8192 gathered rows
#define TOT_ROWS (N_B * C_C)     // 32768 output rows

#define BM 64
#define BN 128
#define BK 64
#define NT (H_H / BK)            // 12 K-steps
#define GBM (M_TOT / BM)         // 128
#define GBN (O_O / BN)           // 6
#define GEMM_BLOCKS (GBM * GBN)  // 768
#define ZBLOCKS 1280
#define XCD_CHUNK (GEMM_BLOCKS / 8)  // 96
#define NGAPS (N_B * (K_K + 1))  // 8200 gap segments
#define EPI_STRIDE 132           // padded fp32 row stride for epilogue tile
#define WGROUPS (O_O * H_H / 8)  // 73728

typedef __attribute__((ext_vector_type(8))) short short8;
typedef __attribute__((ext_vector_type(4))) float f32x4;
typedef __attribute__((ext_vector_type(4))) unsigned short ushort4v;

__device__ __forceinline__ unsigned short f2bf(float f) {
    union { float f; unsigned int u; } v; v.f = f;
    unsigned int r = v.u + 0x7FFFu + ((v.u >> 16) & 1u);  // RNE
    return (unsigned short)(r >> 16);
}

__device__ __forceinline__ unsigned int pk2bf(float a, float b) {
    __hip_bfloat162 h = __float22bfloat162_rn(make_float2(a, b));  // v_cvt_pk_bf16_f32
    return *reinterpret_cast<unsigned int*>(&h);
}

__device__ __forceinline__ void gld16(const void* g, void* l) {
    __builtin_amdgcn_global_load_lds(
        (const __attribute__((address_space(1))) void*)g,
        (__attribute__((address_space(3))) void*)l, 16, 0, 0);
}

// ---------------- Kernel 1: W fp32 -> bf16 (1.13 MB) -----------------------
__global__ __launch_bounds__(256)
void convert_w_kernel(const float* __restrict__ w, unsigned int* __restrict__ wsW) {
    int g = blockIdx.x * 256 + threadIdx.x;
    if (g >= WGROUPS) return;
    const float* s = w + (size_t)g * 8;
    f32x4 v0 = *reinterpret_cast<const f32x4*>(s);
    f32x4 v1 = *reinterpret_cast<const f32x4*>(s + 4);
    uint4 o;
    o.x = pk2bf(v0.x, v0.y); o.y = pk2bf(v0.z, v0.w);
    o.z = pk2bf(v1.x, v1.y); o.w = pk2bf(v1.z, v1.w);
    *reinterpret_cast<uint4*>(wsW + (size_t)g * 4) = o;
}

// ---------------- Kernel 2: fused GEMM + zero-writer -----------------------
// A-IN-REGISTERS variant of the proven R5 structure: the whole 64x768 A tile
// is gathered + bf16-converted ONCE in the prologue (96 VGPRs, static
// indexing via full unroll). The K-loop's As staging is then a pure reg->LDS
// write — the __syncthreads vmcnt(0) drain has no HBM loads left to stall on
// (only L2-resident B gld16, issued a full phase ahead). __syncthreads
// semantics throughout (counted-vmcnt raced in R8/R9 — do not revive).
__global__ __launch_bounds__(256, 3)
void sparse_linear_main(const float* __restrict__ x,
                        const unsigned short* __restrict__ wsW,
                        const float* __restrict__ bias,
                        const int* __restrict__ cidx,
                        float* __restrict__ out)
{
    __shared__ char lds[40960];   // [As 8K][Bs0 16K][Bs1 16K]; epi reuses 33K

    const int tid  = threadIdx.x;
    const int lane = tid & 63;
    const int wid  = tid >> 6;

    if (blockIdx.x >= GEMM_BLOCKS) {
        // ---- zero-writer: one wave per gap between sorted indices ----
        int zw = (blockIdx.x - GEMM_BLOCKS) * 4 + wid;
        for (int g = zw; g < NGAPS; g += ZBLOCKS * 4) {
            int n = g / (K_K + 1);
            int j = g - n * (K_K + 1);
            const int* a = cidx + (n << 10);
            int lo = (j == 0)   ? -1  : a[j - 1];
            int hi = (j == K_K) ? C_C : a[j];
            for (int c = lo + 1; c < hi; ++c) {
                float* o = out + ((size_t)(n * C_C + c)) * O_O;
                f32x4 z = {0.f, 0.f, 0.f, 0.f};
                #pragma unroll
                for (int k2 = 0; k2 < 3; ++k2)
                    __builtin_nontemporal_store(
                        z, reinterpret_cast<f32x4*>(o + (lane + k2 * 64) * 4));
            }
        }
        return;
    }

    // ---- GEMM path ----
    const int logical = (blockIdx.x & 7) * XCD_CHUNK + (blockIdx.x >> 3);
    const int bm = logical / GBN;
    const int bn = logical % GBN;

    char* As  = lds;              // [64][64] bf16 swizzled, single buffer
    char* Bs0 = lds + 8192;       // [128][64] bf16 swizzled, dbuf
    char* Bs1 = lds + 24576;

    const int wr = wid >> 1;      // 32-row half
    const int wc = wid & 1;       // 64-col half
    const int sr = tid >> 4;      // staging row 0..15
    const int sc = tid & 15;      // staging float4 col 0..15

    // A gather offsets (fp32 source)
    int aoff[4];
    #pragma unroll
    for (int p = 0; p < 4; ++p) {
        int row = p * 16 + sr;
        int m = bm * BM + row;
        int n = m >> 10;
        aoff[p] = (n * C_C + cidx[m]) * H_H + sc * 4;
    }
    const int wsw = (sc * 8) ^ ((sr & 7) << 4);   // A LDS write swizzle

    // B source: pre-swizzled per-lane address into bf16 wsW (rule #21)
    const int swzcol = (((lane & 7) ^ (lane >> 3)) << 4);
    const char* bSrc[4];
    #pragma unroll
    for (int q = 0; q < 4; ++q) {
        int row = bn * BN + wid * 32 + q * 8 + (lane >> 3);
        bSrc[q] = (const char*)wsW + (size_t)row * (H_H * 2) + swzcol;
    }

#define STAGE_B(bsb, ktoff) do {                                            \
        _Pragma("unroll") for (int q = 0; q < 4; ++q)                       \
            gld16(bSrc[q] + (ktoff), (bsb) + wid * 4096 + q * 1024);        \
    } while (0)

    f32x4 acc[2][4];
    #pragma unroll
    for (int i = 0; i < 2; ++i)
        #pragma unroll
        for (int j = 0; j < 4; ++j)
            acc[i][j] = (f32x4){0.f, 0.f, 0.f, 0.f};

    const int frow = lane & 15;
    const int fkb  = (lane >> 4) * 16;
    const int rsw  = (frow & 7) << 4;

#define COMPUTE(bsb) do {                                                   \
        _Pragma("unroll") for (int kk = 0; kk < 2; ++kk) {                  \
            short8 af[2], bfr[4];                                           \
            const int kbyte = (kk * 64 + fkb) ^ rsw;                        \
            _Pragma("unroll") for (int mi = 0; mi < 2; ++mi) {              \
                int row = wr * 32 + mi * 16 + frow;                         \
                af[mi] = *reinterpret_cast<const short8*>(As + row * 128 + kbyte); } \
            _Pragma("unroll") for (int nj = 0; nj < 4; ++nj) {              \
                int row = wc * 64 + nj * 16 + frow;                         \
                bfr[nj] = *reinterpret_cast<const short8*>((bsb) + row * 128 + kbyte); } \
            _Pragma("unroll") for (int mi = 0; mi < 2; ++mi)                \
                _Pragma("unroll") for (int nj = 0; nj < 4; ++nj)            \
                    acc[mi][nj] = __builtin_amdgcn_mfma_f32_16x16x32_bf16(  \
                        af[mi], bfr[nj], acc[mi][nj], 0, 0, 0);             \
        } } while (0)

    // Prologue: B(0) in flight; entire A tile -> bf16 registers (96 VGPRs).
    STAGE_B(Bs0, 0);
    uint2 avb[NT][4];
    #pragma unroll
    for (int kt = 0; kt < NT; ++kt) {
        #pragma unroll
        for (int p = 0; p < 4; ++p) {
            f32x4 v = *reinterpret_cast<const f32x4*>(x + aoff[p] + kt * BK);
            avb[kt][p].x = pk2bf(v.x, v.y);
            avb[kt][p].y = pk2bf(v.z, v.w);
        }
    }

    #pragma unroll
    for (int kt = 0; kt < NT; ++kt) {
        char* Bcur = (kt & 1) ? Bs1 : Bs0;
        char* Bnxt = (kt & 1) ? Bs0 : Bs1;
        __syncthreads();                 // #1: As free (COMPUTE(kt-1) done)
        #pragma unroll
        for (int p = 0; p < 4; ++p) {    // reg -> As (no VMEM latency)
            int row = p * 16 + sr;
            *reinterpret_cast<uint2*>(As + row * 128 + wsw) = avb[kt][p];
        }
        __syncthreads();                 // #2: As visible to all
        if (kt + 1 < NT) STAGE_B(Bnxt, (kt + 1) * 128);  // lands during COMPUTE
        COMPUTE(Bcur);
    }

    // ---- epilogue: stage C-tile (+bias) in LDS, 512B NT row segments ----
    const int cbase = bn * BN + wc * 64 + frow;
    float biasv[4];
    #pragma unroll
    for (int nj = 0; nj < 4; ++nj) biasv[nj] = bias[cbase + nj * 16];

    __syncthreads();
    float* epi = (float*)lds;
    const int colb = wc * 64 + frow;
    #pragma unroll
    for (int mi = 0; mi < 2; ++mi) {
        #pragma unroll
        for (int r = 0; r < 4; ++r) {
            int row = wr * 32 + mi * 16 + (lane >> 4) * 4 + r;
            #pragma unroll
            for (int nj = 0; nj < 4; ++nj)
                epi[row * EPI_STRIDE + colb + nj * 16] = acc[mi][nj][r] + biasv[nj];
        }
    }
    __syncthreads();

    #pragma unroll
    for (int it = 0; it < 8; ++it) {
        int chunk = tid + it * 256;           // 64 rows x 32 f32x4
        int row = chunk >> 5;
        int c4  = chunk & 31;
        int grow = bm * BM + row;
        int n = grow >> 10;
        int src = cidx[grow];
        float* o = out + ((size_t)(n * C_C + src)) * O_O + bn * BN + c4 * 4;
        __builtin_nontemporal_store(
            *reinterpret_cast<const f32x4*>(&epi[row * EPI_STRIDE + c4 * 4]),
            reinterpret_cast<f32x4*>(o));
    }
#undef STAGE_B
#undef COMPUTE
}

// ---------------- Fallback (round-4 fused kernel, proven) ------------------
__global__ __launch_bounds__(256, 4)
void sparse_linear_fb(const float* __restrict__ x,
                      const float* __restrict__ w,
                      const float* __restrict__ bias,
                      const int* __restrict__ cidx,
                      float* __restrict__ out)
{
    __shared__ char lds[EPI_STRIDE * BM * 4];

    const int tid  = threadIdx.x;
    const int lane = tid & 63;
    const int wid  = tid >> 6;

    if (blockIdx.x >= GEMM_BLOCKS) {
        int zw = (blockIdx.x - GEMM_BLOCKS) * 4 + wid;
        for (int g = zw; g < NGAPS; g += ZBLOCKS * 4) {
            int n = g / (K_K + 1);
            int j = g - n * (K_K + 1);
            const int* a = cidx + (n << 10);
            int lo = (j == 0)   ? -1  : a[j - 1];
            int hi = (j == K_K) ? C_C : a[j];
            for (int c = lo + 1; c < hi; ++c) {
                float* o = out + ((size_t)(n * C_C + c)) * O_O;
                f32x4 z = {0.f, 0.f, 0.f, 0.f};
                #pragma unroll
                for (int k2 = 0; k2 < 3; ++k2)
                    *reinterpret_cast<f32x4*>(o + (lane + k2 * 64) * 4) = z;
            }
        }
        return;
    }

    const int logical = (blockIdx.x & 7) * XCD_CHUNK + (blockIdx.x >> 3);
    const int bm = logical / GBN;
    const int bn = logical % GBN;

    char* Asb = lds;
    char* Bsb = lds + BM * BK * 2;

    const int wr = wid >> 1;
    const int wc = wid & 1;
    const int sr = tid >> 4;
    const int sc = tid & 15;

    int aoff[4];
    int boff[8];
    #pragma unroll
    for (int p = 0; p < 4; ++p) {
        int row = p * 16 + sr;
        int m = bm * BM + row;
        int n = m >> 10;
        aoff[p] = (n * C_C + cidx[m]) * H_H + sc * 4;
    }
    #pragma unroll
    for (int p = 0; p < 8; ++p) {
        int row = p * 16 + sr;
        boff[p] = (bn * BN + row) * H_H + sc * 4;
    }

    const int wsw = (sc * 8) ^ ((sr & 7) << 4);

    f32x4 av[4], bv[8];
    #pragma unroll
    for (int p = 0; p < 4; ++p) av[p] = *reinterpret_cast<const f32x4*>(x + aoff[p]);
    #pragma unroll
    for (int p = 0; p < 8; ++p) bv[p] = *reinterpret_cast<const f32x4*>(w + boff[p]);

    f32x4 acc[2][4];
    #pragma unroll
    for (int i = 0; i < 2; ++i)
        #pragma unroll
        for (int j = 0; j < 4; ++j)
            acc[i][j] = (f32x4){0.f, 0.f, 0.f, 0.f};

    const int frow = lane & 15;
    const int fkb  = (lane >> 4) * 16;

    for (int kt = 0; kt < NT; ++kt) {
        __syncthreads();
        #pragma unroll
        for (int p = 0; p < 4; ++p) {
            int row = p * 16 + sr;
            ushort4v pa;
            pa.x = f2bf(av[p].x); pa.y = f2bf(av[p].y);
            pa.z = f2bf(av[p].z); pa.w = f2bf(av[p].w);
            *reinterpret_cast<ushort4v*>(Asb + row * 128 + wsw) = pa;
        }
        #pragma unroll
        for (int p = 0; p < 8; ++p) {
            int row = p * 16 + sr;
            ushort4v pb;
            pb.x = f2bf(bv[p].x); pb.y = f2bf(bv[p].y);
            pb.z = f2bf(bv[p].z); pb.w = f2bf(bv[p].w);
            *reinterpret_cast<ushort4v*>(Bsb + row * 128 + wsw) = pb;
        }
        __syncthreads();

        if (kt + 1 < NT) {
            const int kbase = (kt + 1) * BK;
            #pragma unroll
            for (int p = 0; p < 4; ++p)
                av[p] = *reinterpret_cast<const f32x4*>(x + aoff[p] + kbase);
            #pragma unroll
            for (int p = 0; p < 8; ++p)
                bv[p] = *reinterpret_cast<const f32x4*>(w + boff[p] + kbase);
        }

        #pragma unroll
        for (int kk = 0; kk < 2; ++kk) {
            short8 af[2], bf_[4];
            const int kbyte = kk * 64 + fkb;
            #pragma unroll
            for (int mi = 0; mi < 2; ++mi) {
                int row = wr * 32 + mi * 16 + frow;
                af[mi] = *reinterpret_cast<const short8*>(
                    Asb + row * 128 + (kbyte ^ ((row & 7) << 4)));
            }
            #pragma unroll
            for (int nj = 0; nj < 4; ++nj) {
                int row = wc * 64 + nj * 16 + frow;
                bf_[nj] = *reinterpret_cast<const short8*>(
                    Bsb + row * 128 + (kbyte ^ ((row & 7) << 4)));
            }
            #pragma unroll
            for (int mi = 0; mi < 2; ++mi)
                #pragma unroll
                for (int nj = 0; nj < 4; ++nj)
                    acc[mi][nj] = __builtin_amdgcn_mfma_f32_16x16x32_bf16(
                        af[mi], bf_[nj], acc[mi][nj], 0, 0, 0);
        }
    }

    const int cbase = bn * BN + wc * 64 + frow;
    float biasv[4];
    #pragma unroll
    for (int nj = 0; nj < 4; ++nj) biasv[nj] = bias[cbase + nj * 16];

    __syncthreads();
    float* epi2 = (float*)lds;
    const int colb = wc * 64 + frow;
    #pragma unroll
    for (int mi = 0; mi < 2; ++mi) {
        #pragma unroll
        for (int r = 0; r < 4; ++r) {
            int row = wr * 32 + mi * 16 + (lane >> 4) * 4 + r;
            #pragma unroll
            for (int nj = 0; nj < 4; ++nj)
                epi2[row * EPI_STRIDE + colb + nj * 16] = acc[mi][nj][r] + biasv[nj];
        }
    }
    __syncthreads();

    #pragma unroll
    for (int it = 0; it < 8; ++it) {
        int chunk = tid + it * 256;
        int row = chunk >> 5;
        int c4  = chunk & 31;
        int grow = bm * BM + row;
        int n = grow >> 10;
        int src = cidx[grow];
        float* o = out + ((size_t)(n * C_C + src)) * O_O + bn * BN + c4 * 4;
        *reinterpret_cast<f32x4*>(o) =
            *reinterpret_cast<const f32x4*>(&epi2[row * EPI_STRIDE + c4 * 4]);
    }
}

extern "C" void kernel_launch(void* const* d_in, const int* in_sizes, int n_in,
                              void* d_out, int out_size, void* d_ws, size_t ws_size,
                              hipStream_t stream) {
    const float* x    = (const float*)d_in[0];
    const float* w    = (const float*)d_in[1];
    const float* bias = (const float*)d_in[2];
    const int*   cidx = (const int*)d_in[3];
    float* out = (float*)d_out;

    const size_t needed = (size_t)O_O * H_H * 2;   // 1.13 MB bf16 W
    if (ws_size >= needed) {
        unsigned short* wsW = (unsigned short*)d_ws;
        convert_w_kernel<<<(WGROUPS + 255) / 256, 256, 0, stream>>>(
            w, (unsigned int*)wsW);
        sparse_linear_main<<<GEMM_BLOCKS + ZBLOCKS, 256, 0, stream>>>(
            x, wsW, bias, cidx, out);
    } else {
        sparse_linear_fb<<<GEMM_BLOCKS + ZBLOCKS, 256, 0, stream>>>(
            x, w, bias, cidx, out);
    }
}

// Round 12
// 41.110 us; speedup vs baseline: 1.2230x; 1.2230x over previous
//
#include <hip/hip_runtime.h>
#include <hip/hip_bf16.h>

// Problem constants: N=8, C=4096, H=768, O=768, K=1024
#define N_B 8
#define C_C 4096
#define H_H 768
#define O_O 768
#define K_K 1024
#define M_TOT (N_B * K_K)        // 8192 gathered rows
#define TOT_ROWS (N_B * C_C)     // 32768 output rows

#define BM 64
#define BN 128
#define BK 64
#define NT (H_H / BK)            // 12 K-steps
#define GBM (M_TOT / BM)         // 128
#define GBN (O_O / BN)           // 6
#define GEMM_BLOCKS (GBM * GBN)  // 768
#define ZBLOCKS 1280
#define XCD_CHUNK (GEMM_BLOCKS / 8)  // 96
#define NGAPS (N_B * (K_K + 1))  // 8200 gap segments
#define EPI_STRIDE 132           // padded fp32 row stride for epilogue tile
#define WGROUPS (O_O * H_H / 8)  // 73728

typedef __attribute__((ext_vector_type(8))) short short8;
typedef __attribute__((ext_vector_type(4))) float f32x4;
typedef __attribute__((ext_vector_type(4))) unsigned short ushort4v;

__device__ __forceinline__ unsigned short f2bf(float f) {
    union { float f; unsigned int u; } v; v.f = f;
    unsigned int r = v.u + 0x7FFFu + ((v.u >> 16) & 1u);  // RNE
    return (unsigned short)(r >> 16);
}

__device__ __forceinline__ unsigned int pk2bf(float a, float b) {
    __hip_bfloat162 h = __float22bfloat162_rn(make_float2(a, b));  // v_cvt_pk_bf16_f32
    return *reinterpret_cast<unsigned int*>(&h);
}

__device__ __forceinline__ void gld16(const void* g, void* l) {
    __builtin_amdgcn_global_load_lds(
        (const __attribute__((address_space(1))) void*)g,
        (__attribute__((address_space(3))) void*)l, 16, 0, 0);
}

// ---------------- Kernel 1: W fp32 -> bf16 (1.13 MB) -----------------------
__global__ __launch_bounds__(256)
void convert_w_kernel(const float* __restrict__ w, unsigned int* __restrict__ wsW) {
    int g = blockIdx.x * 256 + threadIdx.x;
    if (g >= WGROUPS) return;
    const float* s = w + (size_t)g * 8;
    f32x4 v0 = *reinterpret_cast<const f32x4*>(s);
    f32x4 v1 = *reinterpret_cast<const f32x4*>(s + 4);
    uint4 o;
    o.x = pk2bf(v0.x, v0.y); o.y = pk2bf(v0.z, v0.w);
    o.z = pk2bf(v1.x, v1.y); o.w = pk2bf(v1.z, v1.w);
    *reinterpret_cast<uint4*>(wsW + (size_t)g * 4) = o;
}

// ---------------- Kernel 2: fused GEMM + zero-writer -----------------------
// A-IN-REGISTERS, asm-PINNED (R11 fix): whole 64x768 A tile gathered +
// bf16-converted once in the prologue, then every avb word is pinned with
// asm "+v" — the values become asm outputs, so LLVM cannot rematerialize
// the loads into the K-loop (R11's silent failure, VGPR=84). K-loop VMEM is
// then only the L2-resident B gld16 (issued a full phase ahead) -> the
// __syncthreads vmcnt(0) drain has nothing slow to wait on.
__global__ __launch_bounds__(256, 3)
void sparse_linear_main(const float* __restrict__ x,
                        const unsigned short* __restrict__ wsW,
                        const float* __restrict__ bias,
                        const int* __restrict__ cidx,
                        float* __restrict__ out)
{
    __shared__ char lds[40960];   // [As 8K][Bs0 16K][Bs1 16K]; epi reuses 33K

    const int tid  = threadIdx.x;
    const int lane = tid & 63;
    const int wid  = tid >> 6;

    if (blockIdx.x >= GEMM_BLOCKS) {
        // ---- zero-writer: one wave per gap between sorted indices ----
        int zw = (blockIdx.x - GEMM_BLOCKS) * 4 + wid;
        for (int g = zw; g < NGAPS; g += ZBLOCKS * 4) {
            int n = g / (K_K + 1);
            int j = g - n * (K_K + 1);
            const int* a = cidx + (n << 10);
            int lo = (j == 0)   ? -1  : a[j - 1];
            int hi = (j == K_K) ? C_C : a[j];
            for (int c = lo + 1; c < hi; ++c) {
                float* o = out + ((size_t)(n * C_C + c)) * O_O;
                f32x4 z = {0.f, 0.f, 0.f, 0.f};
                #pragma unroll
                for (int k2 = 0; k2 < 3; ++k2)
                    __builtin_nontemporal_store(
                        z, reinterpret_cast<f32x4*>(o + (lane + k2 * 64) * 4));
            }
        }
        return;
    }

    // ---- GEMM path ----
    const int logical = (blockIdx.x & 7) * XCD_CHUNK + (blockIdx.x >> 3);
    const int bm = logical / GBN;
    const int bn = logical % GBN;

    char* As  = lds;              // [64][64] bf16 swizzled, single buffer
    char* Bs0 = lds + 8192;       // [128][64] bf16 swizzled, dbuf
    char* Bs1 = lds + 24576;

    const int wr = wid >> 1;      // 32-row half
    const int wc = wid & 1;       // 64-col half
    const int sr = tid >> 4;      // staging row 0..15
    const int sc = tid & 15;      // staging float4 col 0..15

    // A gather offsets (fp32 source)
    int aoff[4];
    #pragma unroll
    for (int p = 0; p < 4; ++p) {
        int row = p * 16 + sr;
        int m = bm * BM + row;
        int n = m >> 10;
        aoff[p] = (n * C_C + cidx[m]) * H_H + sc * 4;
    }
    const int wsw = (sc * 8) ^ ((sr & 7) << 4);   // A LDS write swizzle

    // B source: pre-swizzled per-lane address into bf16 wsW (rule #21)
    const int swzcol = (((lane & 7) ^ (lane >> 3)) << 4);
    const char* bSrc[4];
    #pragma unroll
    for (int q = 0; q < 4; ++q) {
        int row = bn * BN + wid * 32 + q * 8 + (lane >> 3);
        bSrc[q] = (const char*)wsW + (size_t)row * (H_H * 2) + swzcol;
    }

#define STAGE_B(bsb, ktoff) do {                                            \
        _Pragma("unroll") for (int q = 0; q < 4; ++q)                       \
            gld16(bSrc[q] + (ktoff), (bsb) + wid * 4096 + q * 1024);        \
    } while (0)

    f32x4 acc[2][4];
    #pragma unroll
    for (int i = 0; i < 2; ++i)
        #pragma unroll
        for (int j = 0; j < 4; ++j)
            acc[i][j] = (f32x4){0.f, 0.f, 0.f, 0.f};

    const int frow = lane & 15;
    const int fkb  = (lane >> 4) * 16;
    const int rsw  = (frow & 7) << 4;

#define COMPUTE(bsb) do {                                                   \
        _Pragma("unroll") for (int kk = 0; kk < 2; ++kk) {                  \
            short8 af[2], bfr[4];                                           \
            const int kbyte = (kk * 64 + fkb) ^ rsw;                        \
            _Pragma("unroll") for (int mi = 0; mi < 2; ++mi) {              \
                int row = wr * 32 + mi * 16 + frow;                         \
                af[mi] = *reinterpret_cast<const short8*>(As + row * 128 + kbyte); } \
            _Pragma("unroll") for (int nj = 0; nj < 4; ++nj) {              \
                int row = wc * 64 + nj * 16 + frow;                         \
                bfr[nj] = *reinterpret_cast<const short8*>((bsb) + row * 128 + kbyte); } \
            _Pragma("unroll") for (int mi = 0; mi < 2; ++mi)                \
                _Pragma("unroll") for (int nj = 0; nj < 4; ++nj)            \
                    acc[mi][nj] = __builtin_amdgcn_mfma_f32_16x16x32_bf16(  \
                        af[mi], bfr[nj], acc[mi][nj], 0, 0, 0);             \
        } } while (0)

    // Prologue: B(0) in flight; entire A tile -> bf16 registers.
    STAGE_B(Bs0, 0);
    uint2 avb[NT][4];
    #pragma unroll
    for (int kt = 0; kt < NT; ++kt) {
        #pragma unroll
        for (int p = 0; p < 4; ++p) {
            f32x4 v = *reinterpret_cast<const f32x4*>(x + aoff[p] + kt * BK);
            avb[kt][p].x = pk2bf(v.x, v.y);
            avb[kt][p].y = pk2bf(v.z, v.w);
        }
    }
    // PIN: make every avb word an asm output -> rematerialization illegal,
    // values must stay resident in VGPRs across the K-loop.
    #pragma unroll
    for (int kt = 0; kt < NT; ++kt)
        #pragma unroll
        for (int p = 0; p < 4; ++p)
            asm volatile("" : "+v"(avb[kt][p].x), "+v"(avb[kt][p].y));

    #pragma unroll
    for (int kt = 0; kt < NT; ++kt) {
        char* Bcur = (kt & 1) ? Bs1 : Bs0;
        char* Bnxt = (kt & 1) ? Bs0 : Bs1;
        __syncthreads();                 // #1: As free (COMPUTE(kt-1) done)
        #pragma unroll
        for (int p = 0; p < 4; ++p) {    // reg -> As (no VMEM latency)
            int row = p * 16 + sr;
            *reinterpret_cast<uint2*>(As + row * 128 + wsw) = avb[kt][p];
        }
        __syncthreads();                 // #2: As visible to all
        if (kt + 1 < NT) STAGE_B(Bnxt, (kt + 1) * 128);  // lands during COMPUTE
        COMPUTE(Bcur);
    }

    // ---- epilogue: stage C-tile (+bias) in LDS, 512B NT row segments ----
    const int cbase = bn * BN + wc * 64 + frow;
    float biasv[4];
    #pragma unroll
    for (int nj = 0; nj < 4; ++nj) biasv[nj] = bias[cbase + nj * 16];

    __syncthreads();
    float* epi = (float*)lds;
    const int colb = wc * 64 + frow;
    #pragma unroll
    for (int mi = 0; mi < 2; ++mi) {
        #pragma unroll
        for (int r = 0; r < 4; ++r) {
            int row = wr * 32 + mi * 16 + (lane >> 4) * 4 + r;
            #pragma unroll
            for (int nj = 0; nj < 4; ++nj)
                epi[row * EPI_STRIDE + colb + nj * 16] = acc[mi][nj][r] + biasv[nj];
        }
    }
    __syncthreads();

    #pragma unroll
    for (int it = 0; it < 8; ++it) {
        int chunk = tid + it * 256;           // 64 rows x 32 f32x4
        int row = chunk >> 5;
        int c4  = chunk & 31;
        int grow = bm * BM + row;
        int n = grow >> 10;
        int src = cidx[grow];
        float* o = out + ((size_t)(n * C_C + src)) * O_O + bn * BN + c4 * 4;
        __builtin_nontemporal_store(
            *reinterpret_cast<const f32x4*>(&epi[row * EPI_STRIDE + c4 * 4]),
            reinterpret_cast<f32x4*>(o));
    }
#undef STAGE_B
#undef COMPUTE
}

// ---------------- Fallback (round-4 fused kernel, proven) ------------------
__global__ __launch_bounds__(256, 4)
void sparse_linear_fb(const float* __restrict__ x,
                      const float* __restrict__ w,
                      const float* __restrict__ bias,
                      const int* __restrict__ cidx,
                      float* __restrict__ out)
{
    __shared__ char lds[EPI_STRIDE * BM * 4];

    const int tid  = threadIdx.x;
    const int lane = tid & 63;
    const int wid  = tid >> 6;

    if (blockIdx.x >= GEMM_BLOCKS) {
        int zw = (blockIdx.x - GEMM_BLOCKS) * 4 + wid;
        for (int g = zw; g < NGAPS; g += ZBLOCKS * 4) {
            int n = g / (K_K + 1);
            int j = g - n * (K_K + 1);
            const int* a = cidx + (n << 10);
            int lo = (j == 0)   ? -1  : a[j - 1];
            int hi = (j == K_K) ? C_C : a[j];
            for (int c = lo + 1; c < hi; ++c) {
                float* o = out + ((size_t)(n * C_C + c)) * O_O;
                f32x4 z = {0.f, 0.f, 0.f, 0.f};
                #pragma unroll
                for (int k2 = 0; k2 < 3; ++k2)
                    *reinterpret_cast<f32x4*>(o + (lane + k2 * 64) * 4) = z;
            }
        }
        return;
    }

    const int logical = (blockIdx.x & 7) * XCD_CHUNK + (blockIdx.x >> 3);
    const int bm = logical / GBN;
    const int bn = logical % GBN;

    char* Asb = lds;
    char* Bsb = lds + BM * BK * 2;

    const int wr = wid >> 1;
    const int wc = wid & 1;
    const int sr = tid >> 4;
    const int sc = tid & 15;

    int aoff[4];
    int boff[8];
    #pragma unroll
    for (int p = 0; p < 4; ++p) {
        int row = p * 16 + sr;
        int m = bm * BM + row;
        int n = m >> 10;
        aoff[p] = (n * C_C + cidx[m]) * H_H + sc * 4;
    }
    #pragma unroll
    for (int p = 0; p < 8; ++p) {
        int row = p * 16 + sr;
        boff[p] = (bn * BN + row) * H_H + sc * 4;
    }

    const int wsw = (sc * 8) ^ ((sr & 7) << 4);

    f32x4 av[4], bv[8];
    #pragma unroll
    for (int p = 0; p < 4; ++p) av[p] = *reinterpret_cast<const f32x4*>(x + aoff[p]);
    #pragma unroll
    for (int p = 0; p < 8; ++p) bv[p] = *reinterpret_cast<const f32x4*>(w + boff[p]);

    f32x4 acc[2][4];
    #pragma unroll
    for (int i = 0; i < 2; ++i)
        #pragma unroll
        for (int j = 0; j < 4; ++j)
            acc[i][j] = (f32x4){0.f, 0.f, 0.f, 0.f};

    const int frow = lane & 15;
    const int fkb  = (lane >> 4) * 16;

    for (int kt = 0; kt < NT; ++kt) {
        __syncthreads();
        #pragma unroll
        for (int p = 0; p < 4; ++p) {
            int row = p * 16 + sr;
            ushort4v pa;
            pa.x = f2bf(av[p].x); pa.y = f2bf(av[p].y);
            pa.z = f2bf(av[p].z); pa.w = f2bf(av[p].w);
            *reinterpret_cast<ushort4v*>(Asb + row * 128 + wsw) = pa;
        }
        #pragma unroll
        for (int p = 0; p < 8; ++p) {
            int row = p * 16 + sr;
            ushort4v pb;
            pb.x = f2bf(bv[p].x); pb.y = f2bf(bv[p].y);
            pb.z = f2bf(bv[p].z); pb.w = f2bf(bv[p].w);
            *reinterpret_cast<ushort4v*>(Bsb + row * 128 + wsw) = pb;
        }
        __syncthreads();

        if (kt + 1 < NT) {
            const int kbase = (kt + 1) * BK;
            #pragma unroll
            for (int p = 0; p < 4; ++p)
                av[p] = *reinterpret_cast<const f32x4*>(x + aoff[p] + kbase);
            #pragma unroll
            for (int p = 0; p < 8; ++p)
                bv[p] = *reinterpret_cast<const f32x4*>(w + boff[p] + kbase);
        }

        #pragma unroll
        for (int kk = 0; kk < 2; ++kk) {
            short8 af[2], bf_[4];
            const int kbyte = kk * 64 + fkb;
            #pragma unroll
            for (int mi = 0; mi < 2; ++mi) {
                int row = wr * 32 + mi * 16 + frow;
                af[mi] = *reinterpret_cast<const short8*>(
                    Asb + row * 128 + (kbyte ^ ((row & 7) << 4)));
            }
            #pragma unroll
            for (int nj = 0; nj < 4; ++nj) {
                int row = wc * 64 + nj * 16 + frow;
                bf_[nj] = *reinterpret_cast<const short8*>(
                    Bsb + row * 128 + (kbyte ^ ((row & 7) << 4)));
            }
            #pragma unroll
            for (int mi = 0; mi < 2; ++mi)
                #pragma unroll
                for (int nj = 0; nj < 4; ++nj)
                    acc[mi][nj] = __builtin_amdgcn_mfma_f32_16x16x32_bf16(
                        af[mi], bf_[nj], acc[mi][nj], 0, 0, 0);
        }
    }

    const int cbase = bn * BN + wc * 64 + frow;
    float biasv[4];
    #pragma unroll
    for (int nj = 0; nj < 4; ++nj) biasv[nj] = bias[cbase + nj * 16];

    __syncthreads();
    float* epi2 = (float*)lds;
    const int colb = wc * 64 + frow;
    #pragma unroll
    for (int mi = 0; mi < 2; ++mi) {
        #pragma unroll
        for (int r = 0; r < 4; ++r) {
            int row = wr * 32 + mi * 16 + (lane >> 4) * 4 + r;
            #pragma unroll
            for (int nj = 0; nj < 4; ++nj)
                epi2[row * EPI_STRIDE + colb + nj * 16] = acc[mi][nj][r] + biasv[nj];
        }
    }
    __syncthreads();

    #pragma unroll
    for (int it = 0; it < 8; ++it) {
        int chunk = tid + it * 256;
        int row = chunk >> 5;
        int c4  = chunk & 31;
        int grow = bm * BM + row;
        int n = grow >> 10;
        int src = cidx[grow];
        float* o = out + ((size_t)(n * C_C + src)) * O_O + bn * BN + c4 * 4;
        *reinterpret_cast<f32x4*>(o) =
            *reinterpret_cast<const f32x4*>(&epi2[row * EPI_STRIDE + c4 * 4]);
    }
}

extern "C" void kernel_launch(void* const* d_in, const int* in_sizes, int n_in,
                              void* d_out, int out_size, void* d_ws, size_t ws_size,
                              hipStream_t stream) {
    const float* x    = (const float*)d_in[0];
    const float* w    = (const float*)d_in[1];
    const float* bias = (const float*)d_in[2];
    const int*   cidx = (const int*)d_in[3];
    float* out = (float*)d_out;

    const size_t needed = (size_t)O_O * H_H * 2;   // 1.13 MB bf16 W
    if (ws_size >= needed) {
        unsigned short* wsW = (unsigned short*)d_ws;
        convert_w_kernel<<<(WGROUPS + 255) / 256, 256, 0, stream>>>(
            w, (unsigned int*)wsW);
        sparse_linear_main<<<GEMM_BLOCKS + ZBLOCKS, 256, 0, stream>>>(
            x, wsW, bias, cidx, out);
    } else {
        sparse_linear_fb<<<GEMM_BLOCKS + ZBLOCKS, 256, 0, stream>>>(
            x, w, bias, cidx, out);
    }
}

// Round 13
// 32.638 us; speedup vs baseline: 1.5404x; 1.2596x over previous
//
#include <hip/hip_runtime.h>
#include <hip/hip_bf16.h>

// Problem constants: N=8, C=4096, H=768, O=768, K=1024
#define N_B 8
#define C_C 4096
#define H_H 768
#define O_O 768
#define K_K 1024
#define M_TOT (N_B * K_K)        // 8192 gathered rows
#define TOT_ROWS (N_B * C_C)     // 32768 output rows

#define BM 64
#define BN 128
#define BK 64
#define NT (H_H / BK)            // 12 K-steps
#define GBM (M_TOT / BM)         // 128
#define GBN (O_O / BN)           // 6
#define GEMM_BLOCKS (GBM * GBN)  // 768
#define ZBLOCKS 1280
#define XCD_CHUNK (GEMM_BLOCKS / 8)  // 96
#define NGAPS (N_B * (K_K + 1))  // 8200 gap segments
#define EPI_STRIDE 132           // padded fp32 row stride for epilogue tile
#define WGROUPS (O_O * H_H / 8)  // 73728

typedef __attribute__((ext_vector_type(8))) short short8;
typedef __attribute__((ext_vector_type(4))) float f32x4;
typedef __attribute__((ext_vector_type(4))) unsigned short ushort4v;

__device__ __forceinline__ unsigned short f2bf(float f) {
    union { float f; unsigned int u; } v; v.f = f;
    unsigned int r = v.u + 0x7FFFu + ((v.u >> 16) & 1u);  // RNE
    return (unsigned short)(r >> 16);
}

__device__ __forceinline__ unsigned int pk2bf(float a, float b) {
    __hip_bfloat162 h = __float22bfloat162_rn(make_float2(a, b));  // v_cvt_pk_bf16_f32
    return *reinterpret_cast<unsigned int*>(&h);
}

__device__ __forceinline__ void gld16(const void* g, void* l) {
    __builtin_amdgcn_global_load_lds(
        (const __attribute__((address_space(1))) void*)g,
        (__attribute__((address_space(3))) void*)l, 16, 0, 0);
}

// ---------------- Kernel 1: W fp32 -> bf16 (1.13 MB, ~0.5us) ---------------
__global__ __launch_bounds__(256)
void convert_w_kernel(const float* __restrict__ w, unsigned int* __restrict__ wsW) {
    int g = blockIdx.x * 256 + threadIdx.x;
    if (g >= WGROUPS) return;
    const float* s = w + (size_t)g * 8;
    f32x4 v0 = *reinterpret_cast<const f32x4*>(s);
    f32x4 v1 = *reinterpret_cast<const f32x4*>(s + 4);
    uint4 o;
    o.x = pk2bf(v0.x, v0.y); o.y = pk2bf(v0.z, v0.w);
    o.z = pk2bf(v1.x, v1.y); o.w = pk2bf(v1.z, v1.w);
    *reinterpret_cast<uint4*>(wsW + (size_t)g * 4) = o;
}

// ---------------- Kernel 2: fused GEMM + zero-writer (PROVEN R5, 32.6us) ---
// Session plateau: epilogue LDS-staging (-30%), XCD chunking (FETCH 80->23MB),
// gap-walk zeroing + fused overlap are the real wins. The remaining ~12us gap
// to the ~20us traffic floor is the per-K-step __syncthreads vmcnt(0) drain;
// counted-vmcnt (R8/R9) races, A-in-regs (R11/R12) breaks regalloc. Do not
// revive without a multi-run race screen / asm inspection.
__global__ __launch_bounds__(256, 4)
void sparse_linear_main(const float* __restrict__ x,
                        const unsigned short* __restrict__ wsW,
                        const float* __restrict__ bias,
                        const int* __restrict__ cidx,
                        float* __restrict__ out)
{
    __shared__ char lds[40960];   // [As 8K][Bs0 16K][Bs1 16K]; epi reuses 33K

    const int tid  = threadIdx.x;
    const int lane = tid & 63;
    const int wid  = tid >> 6;

    if (blockIdx.x >= GEMM_BLOCKS) {
        // ---- zero-writer: one wave per gap between sorted indices ----
        int zw = (blockIdx.x - GEMM_BLOCKS) * 4 + wid;
        for (int g = zw; g < NGAPS; g += ZBLOCKS * 4) {
            int n = g / (K_K + 1);
            int j = g - n * (K_K + 1);
            const int* a = cidx + (n << 10);
            int lo = (j == 0)   ? -1  : a[j - 1];
            int hi = (j == K_K) ? C_C : a[j];
            for (int c = lo + 1; c < hi; ++c) {
                float* o = out + ((size_t)(n * C_C + c)) * O_O;
                f32x4 z = {0.f, 0.f, 0.f, 0.f};
                #pragma unroll
                for (int k2 = 0; k2 < 3; ++k2)
                    __builtin_nontemporal_store(
                        z, reinterpret_cast<f32x4*>(o + (lane + k2 * 64) * 4));
            }
        }
        return;
    }

    // ---- GEMM path ----
    const int logical = (blockIdx.x & 7) * XCD_CHUNK + (blockIdx.x >> 3);
    const int bm = logical / GBN;
    const int bn = logical % GBN;

    char* As  = lds;              // [64][64] bf16 swizzled, single buffer
    char* Bs0 = lds + 8192;       // [128][64] bf16 swizzled, dbuf
    char* Bs1 = lds + 24576;

    const int wr = wid >> 1;      // 32-row half
    const int wc = wid & 1;       // 64-col half
    const int sr = tid >> 4;      // staging row 0..15
    const int sc = tid & 15;      // staging float4 col 0..15

    // A gather offsets (fp32 source)
    int aoff[4];
    #pragma unroll
    for (int p = 0; p < 4; ++p) {
        int row = p * 16 + sr;
        int m = bm * BM + row;
        int n = m >> 10;
        aoff[p] = (n * C_C + cidx[m]) * H_H + sc * 4;
    }
    const int wsw = (sc * 8) ^ ((sr & 7) << 4);   // A LDS write swizzle

    // B source: pre-swizzled per-lane address into bf16 wsW (rule #21:
    // linear LDS dest + inverse-swizzled source + swizzled read).
    const int swzcol = (((lane & 7) ^ (lane >> 3)) << 4);
    const char* bSrc[4];
    #pragma unroll
    for (int q = 0; q < 4; ++q) {
        int row = bn * BN + wid * 32 + q * 8 + (lane >> 3);
        bSrc[q] = (const char*)wsW + (size_t)row * (H_H * 2) + swzcol;
    }

#define STAGE_B(bsb, ktoff) do {                                            \
        _Pragma("unroll") for (int q = 0; q < 4; ++q)                       \
            gld16(bSrc[q] + (ktoff), (bsb) + wid * 4096 + q * 1024);        \
    } while (0)

    f32x4 acc[2][4];
    #pragma unroll
    for (int i = 0; i < 2; ++i)
        #pragma unroll
        for (int j = 0; j < 4; ++j)
            acc[i][j] = (f32x4){0.f, 0.f, 0.f, 0.f};

    const int frow = lane & 15;
    const int fkb  = (lane >> 4) * 16;
    const int rsw  = (frow & 7) << 4;

#define COMPUTE(bsb) do {                                                   \
        _Pragma("unroll") for (int kk = 0; kk < 2; ++kk) {                  \
            short8 af[2], bfr[4];                                           \
            const int kbyte = (kk * 64 + fkb) ^ rsw;                        \
            _Pragma("unroll") for (int mi = 0; mi < 2; ++mi) {              \
                int row = wr * 32 + mi * 16 + frow;                         \
                af[mi] = *reinterpret_cast<const short8*>(As + row * 128 + kbyte); } \
            _Pragma("unroll") for (int nj = 0; nj < 4; ++nj) {              \
                int row = wc * 64 + nj * 16 + frow;                         \
                bfr[nj] = *reinterpret_cast<const short8*>((bsb) + row * 128 + kbyte); } \
            _Pragma("unroll") for (int mi = 0; mi < 2; ++mi)                \
                _Pragma("unroll") for (int nj = 0; nj < 4; ++nj)            \
                    acc[mi][nj] = __builtin_amdgcn_mfma_f32_16x16x32_bf16(  \
                        af[mi], bfr[nj], acc[mi][nj], 0, 0, 0);             \
        } } while (0)

    // Prologue: B(0) in flight; A(0) in regs
    STAGE_B(Bs0, 0);
    f32x4 av[4];
    #pragma unroll
    for (int p = 0; p < 4; ++p) av[p] = *reinterpret_cast<const f32x4*>(x + aoff[p]);

    #pragma unroll
    for (int kt = 0; kt < NT; ++kt) {
        char* Bcur = (kt & 1) ? Bs1 : Bs0;
        char* Bnxt = (kt & 1) ? Bs0 : Bs1;
        __syncthreads();                 // #1: COMPUTE(kt-1) done; drains B(kt)
        #pragma unroll
        for (int p = 0; p < 4; ++p) {    // write A(kt) -> As (cvt_pk)
            int row = p * 16 + sr;
            uint2 pa;
            pa.x = pk2bf(av[p].x, av[p].y);
            pa.y = pk2bf(av[p].z, av[p].w);
            *reinterpret_cast<uint2*>(As + row * 128 + wsw) = pa;
        }
        __syncthreads();                 // #2: As visible to all
        if (kt + 1 < NT) {
            STAGE_B(Bnxt, (kt + 1) * 128);      // lands during COMPUTE(kt)
            const int kbase = (kt + 1) * BK;
            #pragma unroll
            for (int p = 0; p < 4; ++p)         // A(kt+1) regs
                av[p] = *reinterpret_cast<const f32x4*>(x + aoff[p] + kbase);
        }
        COMPUTE(Bcur);
    }

    // ---- epilogue: stage C-tile (+bias) in LDS, 512B row segments ----
    const int cbase = bn * BN + wc * 64 + frow;
    float biasv[4];
    #pragma unroll
    for (int nj = 0; nj < 4; ++nj) biasv[nj] = bias[cbase + nj * 16];

    __syncthreads();
    float* epi = (float*)lds;
    const int colb = wc * 64 + frow;
    #pragma unroll
    for (int mi = 0; mi < 2; ++mi) {
        #pragma unroll
        for (int r = 0; r < 4; ++r) {
            int row = wr * 32 + mi * 16 + (lane >> 4) * 4 + r;
            #pragma unroll
            for (int nj = 0; nj < 4; ++nj)
                epi[row * EPI_STRIDE + colb + nj * 16] = acc[mi][nj][r] + biasv[nj];
        }
    }
    __syncthreads();

    #pragma unroll
    for (int it = 0; it < 8; ++it) {
        int chunk = tid + it * 256;           // 64 rows x 32 f32x4
        int row = chunk >> 5;
        int c4  = chunk & 31;
        int grow = bm * BM + row;
        int n = grow >> 10;
        int src = cidx[grow];
        float* o = out + ((size_t)(n * C_C + src)) * O_O + bn * BN + c4 * 4;
        *reinterpret_cast<f32x4*>(o) =
            *reinterpret_cast<const f32x4*>(&epi[row * EPI_STRIDE + c4 * 4]);
    }
#undef STAGE_B
#undef COMPUTE
}

// ---------------- Fallback (round-4 fused kernel, proven 33.2us) -----------
__global__ __launch_bounds__(256, 4)
void sparse_linear_fb(const float* __restrict__ x,
                      const float* __restrict__ w,
                      const float* __restrict__ bias,
                      const int* __restrict__ cidx,
                      float* __restrict__ out)
{
    __shared__ char lds[EPI_STRIDE * BM * 4];

    const int tid  = threadIdx.x;
    const int lane = tid & 63;
    const int wid  = tid >> 6;

    if (blockIdx.x >= GEMM_BLOCKS) {
        int zw = (blockIdx.x - GEMM_BLOCKS) * 4 + wid;
        for (int g = zw; g < NGAPS; g += ZBLOCKS * 4) {
            int n = g / (K_K + 1);
            int j = g - n * (K_K + 1);
            const int* a = cidx + (n << 10);
            int lo = (j == 0)   ? -1  : a[j - 1];
            int hi = (j == K_K) ? C_C : a[j];
            for (int c = lo + 1; c < hi; ++c) {
                float* o = out + ((size_t)(n * C_C + c)) * O_O;
                f32x4 z = {0.f, 0.f, 0.f, 0.f};
                #pragma unroll
                for (int k2 = 0; k2 < 3; ++k2)
                    *reinterpret_cast<f32x4*>(o + (lane + k2 * 64) * 4) = z;
            }
        }
        return;
    }

    const int logical = (blockIdx.x & 7) * XCD_CHUNK + (blockIdx.x >> 3);
    const int bm = logical / GBN;
    const int bn = logical % GBN;

    char* Asb = lds;
    char* Bsb = lds + BM * BK * 2;

    const int wr = wid >> 1;
    const int wc = wid & 1;
    const int sr = tid >> 4;
    const int sc = tid & 15;

    int aoff[4];
    int boff[8];
    #pragma unroll
    for (int p = 0; p < 4; ++p) {
        int row = p * 16 + sr;
        int m = bm * BM + row;
        int n = m >> 10;
        aoff[p] = (n * C_C + cidx[m]) * H_H + sc * 4;
    }
    #pragma unroll
    for (int p = 0; p < 8; ++p) {
        int row = p * 16 + sr;
        boff[p] = (bn * BN + row) * H_H + sc * 4;
    }

    const int wsw = (sc * 8) ^ ((sr & 7) << 4);

    f32x4 av[4], bv[8];
    #pragma unroll
    for (int p = 0; p < 4; ++p) av[p] = *reinterpret_cast<const f32x4*>(x + aoff[p]);
    #pragma unroll
    for (int p = 0; p < 8; ++p) bv[p] = *reinterpret_cast<const f32x4*>(w + boff[p]);

    f32x4 acc[2][4];
    #pragma unroll
    for (int i = 0; i < 2; ++i)
        #pragma unroll
        for (int j = 0; j < 4; ++j)
            acc[i][j] = (f32x4){0.f, 0.f, 0.f, 0.f};

    const int frow = lane & 15;
    const int fkb  = (lane >> 4) * 16;

    for (int kt = 0; kt < NT; ++kt) {
        __syncthreads();
        #pragma unroll
        for (int p = 0; p < 4; ++p) {
            int row = p * 16 + sr;
            ushort4v pa;
            pa.x = f2bf(av[p].x); pa.y = f2bf(av[p].y);
            pa.z = f2bf(av[p].z); pa.w = f2bf(av[p].w);
            *reinterpret_cast<ushort4v*>(Asb + row * 128 + wsw) = pa;
        }
        #pragma unroll
        for (int p = 0; p < 8; ++p) {
            int row = p * 16 + sr;
            ushort4v pb;
            pb.x = f2bf(bv[p].x); pb.y = f2bf(bv[p].y);
            pb.z = f2bf(bv[p].z); pb.w = f2bf(bv[p].w);
            *reinterpret_cast<ushort4v*>(Bsb + row * 128 + wsw) = pb;
        }
        __syncthreads();

        if (kt + 1 < NT) {
            const int kbase = (kt + 1) * BK;
            #pragma unroll
            for (int p = 0; p < 4; ++p)
                av[p] = *reinterpret_cast<const f32x4*>(x + aoff[p] + kbase);
            #pragma unroll
            for (int p = 0; p < 8; ++p)
                bv[p] = *reinterpret_cast<const f32x4*>(w + boff[p] + kbase);
        }

        #pragma unroll
        for (int kk = 0; kk < 2; ++kk) {
            short8 af[2], bf_[4];
            const int kbyte = kk * 64 + fkb;
            #pragma unroll
            for (int mi = 0; mi < 2; ++mi) {
                int row = wr * 32 + mi * 16 + frow;
                af[mi] = *reinterpret_cast<const short8*>(
                    Asb + row * 128 + (kbyte ^ ((row & 7) << 4)));
            }
            #pragma unroll
            for (int nj = 0; nj < 4; ++nj) {
                int row = wc * 64 + nj * 16 + frow;
                bf_[nj] = *reinterpret_cast<const short8*>(
                    Bsb + row * 128 + (kbyte ^ ((row & 7) << 4)));
            }
            #pragma unroll
            for (int mi = 0; mi < 2; ++mi)
                #pragma unroll
                for (int nj = 0; nj < 4; ++nj)
                    acc[mi][nj] = __builtin_amdgcn_mfma_f32_16x16x32_bf16(
                        af[mi], bf_[nj], acc[mi][nj], 0, 0, 0);
        }
    }

    const int cbase = bn * BN + wc * 64 + frow;
    float biasv[4];
    #pragma unroll
    for (int nj = 0; nj < 4; ++nj) biasv[nj] = bias[cbase + nj * 16];

    __syncthreads();
    float* epi2 = (float*)lds;
    const int colb = wc * 64 + frow;
    #pragma unroll
    for (int mi = 0; mi < 2; ++mi) {
        #pragma unroll
        for (int r = 0; r < 4; ++r) {
            int row = wr * 32 + mi * 16 + (lane >> 4) * 4 + r;
            #pragma unroll
            for (int nj = 0; nj < 4; ++nj)
                epi2[row * EPI_STRIDE + colb + nj * 16] = acc[mi][nj][r] + biasv[nj];
        }
    }
    __syncthreads();

    #pragma unroll
    for (int it = 0; it < 8; ++it) {
        int chunk = tid + it * 256;
        int row = chunk >> 5;
        int c4  = chunk & 31;
        int grow = bm * BM + row;
        int n = grow >> 10;
        int src = cidx[grow];
        float* o = out + ((size_t)(n * C_C + src)) * O_O + bn * BN + c4 * 4;
        *reinterpret_cast<f32x4*>(o) =
            *reinterpret_cast<const f32x4*>(&epi2[row * EPI_STRIDE + c4 * 4]);
    }
}

extern "C" void kernel_launch(void* const* d_in, const int* in_sizes, int n_in,
                              void* d_out, int out_size, void* d_ws, size_t ws_size,
                              hipStream_t stream) {
    const float* x    = (const float*)d_in[0];
    const float* w    = (const float*)d_in[1];
    const float* bias = (const float*)d_in[2];
    const int*   cidx = (const int*)d_in[3];
    float* out = (float*)d_out;

    const size_t needed = (size_t)O_O * H_H * 2;   // 1.13 MB bf16 W
    if (ws_size >= needed) {
        unsigned short* wsW = (unsigned short*)d_ws;
        convert_w_kernel<<<(WGROUPS + 255) / 256, 256, 0, stream>>>(
            w, (unsigned int*)wsW);
        sparse_linear_main<<<GEMM_BLOCKS + ZBLOCKS, 256, 0, stream>>>(
            x, wsW, bias, cidx, out);
    } else {
        sparse_linear_fb<<<GEMM_BLOCKS + ZBLOCKS, 256, 0, stream>>>(
            x, w, bias, cidx, out);
    }
}